// Round 5
// baseline (765.743 us; speedup 1.0000x reference)
//
#include <hip/hip_runtime.h>

#define NTOK 16384
#define HDIM 2048
#define HD4  512
#define NG   4
#define EPG  16
#define NE   64

// ---------------------------------------------------------------------------
// Kernel 1: h = gelu_exact(x @ Wc1 + bc1)   [16384x2048] @ [2048x512]
// BM=128, BN=128, BK=16, 256 threads, 8x8 microtile per thread.
// ---------------------------------------------------------------------------
__global__ __launch_bounds__(256) void gemm_conf_kernel(
    const float* __restrict__ x, const float* __restrict__ Wc1,
    const float* __restrict__ bc1, float* __restrict__ h)
{
    __shared__ float As[16][132];   // k-major, padded (conflict-free writes)
    __shared__ float Bs[16][132];
    const int tid = threadIdx.x;
    const int bm = blockIdx.x;      // 0..127
    const int bn = blockIdx.y;      // 0..3
    const int tr = tid >> 4, tc = tid & 15;

    float acc[8][8];
#pragma unroll
    for (int i = 0; i < 8; ++i)
#pragma unroll
        for (int j = 0; j < 8; ++j) acc[i][j] = 0.0f;

    const float* xb = x + (size_t)bm * 128 * HDIM;
    const float* wb = Wc1 + bn * 128;

    for (int k0 = 0; k0 < HDIM; k0 += 16) {
#pragma unroll
        for (int i = 0; i < 2; ++i) {           // A tile: 128 rows x 16 k
            int f4i = tid + i * 256;
            int arow = f4i >> 2, ak4 = f4i & 3;
            float4 v = *(const float4*)(xb + (size_t)arow * HDIM + k0 + ak4 * 4);
            As[ak4 * 4 + 0][arow] = v.x;
            As[ak4 * 4 + 1][arow] = v.y;
            As[ak4 * 4 + 2][arow] = v.z;
            As[ak4 * 4 + 3][arow] = v.w;
        }
#pragma unroll
        for (int i = 0; i < 2; ++i) {           // B tile: 16 k x 128 cols
            int f4i = tid + i * 256;
            int brow = f4i >> 5, bc4 = f4i & 31;
            *(float4*)&Bs[brow][bc4 * 4] =
                *(const float4*)(wb + (size_t)(k0 + brow) * HD4 + bc4 * 4);
        }
        __syncthreads();
#pragma unroll
        for (int k = 0; k < 16; ++k) {
            float av[8], bv[8];
            *(float4*)&av[0] = *(const float4*)&As[k][tr * 8];
            *(float4*)&av[4] = *(const float4*)&As[k][tr * 8 + 4];
            *(float4*)&bv[0] = *(const float4*)&Bs[k][tc * 8];
            *(float4*)&bv[4] = *(const float4*)&Bs[k][tc * 8 + 4];
#pragma unroll
            for (int i = 0; i < 8; ++i)
#pragma unroll
                for (int j = 0; j < 8; ++j)
                    acc[i][j] = fmaf(av[i], bv[j], acc[i][j]);
        }
        __syncthreads();
    }

    const int col0 = bn * 128 + tc * 8;
    float bb[8];
#pragma unroll
    for (int j = 0; j < 8; ++j) bb[j] = bc1[col0 + j];
#pragma unroll
    for (int i = 0; i < 8; ++i) {
        const int row = bm * 128 + tr * 8 + i;
        float o[8];
#pragma unroll
        for (int j = 0; j < 8; ++j) {
            float v = acc[i][j] + bb[j];
            // exact GELU: 0.5*x*(1+erf(x/sqrt(2)))
            o[j] = 0.5f * v * (1.0f + erff(v * 0.70710678118654752440f));
        }
        float* dst = h + (size_t)row * HD4 + col0;
        *(float4*)(dst)     = *(float4*)&o[0];
        *(float4*)(dst + 4) = *(float4*)&o[4];
    }
}

// ---------------------------------------------------------------------------
// Kernel 2: conf[n] = sigmoid(h[n,:] . Wc2 + bc2), one wave per row
// ---------------------------------------------------------------------------
__global__ __launch_bounds__(256) void conf_reduce_kernel(
    const float* __restrict__ h, const float* __restrict__ Wc2,
    const float* __restrict__ bc2, float* __restrict__ conf)
{
    const int wv = threadIdx.x >> 6, lane = threadIdx.x & 63;
    const int n = blockIdx.x * 4 + wv;
    const float* hr = h + (size_t)n * HD4;
    float s = 0.0f;
#pragma unroll
    for (int t = 0; t < 2; ++t) {
        const int j = t * 256 + lane * 4;
        float4 hv = *(const float4*)(hr + j);
        float4 w4 = *(const float4*)(Wc2 + j);
        s = fmaf(hv.x, w4.x, s);
        s = fmaf(hv.y, w4.y, s);
        s = fmaf(hv.z, w4.z, s);
        s = fmaf(hv.w, w4.w, s);
    }
#pragma unroll
    for (int m = 32; m; m >>= 1) s += __shfl_xor(s, m, 64);
    if (lane == 0) {
        float v = s + bc2[0];
        conf[n] = 1.0f / (1.0f + expf(-v));
    }
}

// ---------------------------------------------------------------------------
// Kernel 3: El = x @ We_flat   [16384x2048] @ [2048x64] (col j = We[j/16][:, j%16])
// BM=64, BN=64, BK=16, 256 threads, 4x4 microtile, two-level K accumulation.
// ---------------------------------------------------------------------------
__global__ __launch_bounds__(256) void gemm_experts_kernel(
    const float* __restrict__ x, const float* __restrict__ We,
    float* __restrict__ El)
{
    __shared__ float As[16][68];
    __shared__ float Bs[16][68];
    const int tid = threadIdx.x;
    const int bm = blockIdx.x;      // 0..255
    const int tr = tid >> 4, tc = tid & 15;

    float acc[4][4];
#pragma unroll
    for (int i = 0; i < 4; ++i)
#pragma unroll
        for (int j = 0; j < 4; ++j) acc[i][j] = 0.0f;

    const float* xb = x + (size_t)bm * 64 * HDIM;
    const int arow = tid >> 2, ak4 = tid & 3;
    const int bkk = tid >> 4;            // k-row 0..15
    const int bgrp = (tid >> 2) & 3;     // group 0..3
    const int be4 = tid & 3;             // e-quad 0..3

    for (int k0 = 0; k0 < HDIM; k0 += 16) {
        float4 va = *(const float4*)(xb + (size_t)arow * HDIM + k0 + ak4 * 4);
        As[ak4 * 4 + 0][arow] = va.x;
        As[ak4 * 4 + 1][arow] = va.y;
        As[ak4 * 4 + 2][arow] = va.z;
        As[ak4 * 4 + 3][arow] = va.w;
        // We[g][k][e] -> Bs[k][g*16+e]
        *(float4*)&Bs[bkk][bgrp * 16 + be4 * 4] =
            *(const float4*)(We + (size_t)bgrp * HDIM * EPG
                             + (size_t)(k0 + bkk) * EPG + be4 * 4);
        __syncthreads();

        float acc_t[4][4];      // per-K-tile partial (reduces fp32 rounding drift)
#pragma unroll
        for (int i = 0; i < 4; ++i)
#pragma unroll
            for (int j = 0; j < 4; ++j) acc_t[i][j] = 0.0f;
#pragma unroll
        for (int k = 0; k < 16; ++k) {
            float av[4], bv[4];
            *(float4*)av = *(const float4*)&As[k][tr * 4];
            *(float4*)bv = *(const float4*)&Bs[k][tc * 4];
#pragma unroll
            for (int i = 0; i < 4; ++i)
#pragma unroll
                for (int j = 0; j < 4; ++j)
                    acc_t[i][j] = fmaf(av[i], bv[j], acc_t[i][j]);
        }
#pragma unroll
        for (int i = 0; i < 4; ++i)
#pragma unroll
            for (int j = 0; j < 4; ++j) acc[i][j] += acc_t[i][j];
        __syncthreads();
    }
#pragma unroll
    for (int i = 0; i < 4; ++i) {
        float o[4] = {acc[i][0], acc[i][1], acc[i][2], acc[i][3]};
        *(float4*)(El + (size_t)(bm * 64 + tr * 4 + i) * NE + tc * 4) = *(float4*)o;
    }
}

// ---------------------------------------------------------------------------
// Kernel 4: Gl = x @ Wg   [16384x2048] @ [2048x4], one wave per row
// ---------------------------------------------------------------------------
__global__ __launch_bounds__(256) void gemv_gates_kernel(
    const float* __restrict__ x, const float* __restrict__ Wg,
    float* __restrict__ Gl)
{
    const int wv = threadIdx.x >> 6, lane = threadIdx.x & 63;
    const int n = blockIdx.x * 4 + wv;
    const float* xr = x + (size_t)n * HDIM;
    float a0 = 0, a1 = 0, a2 = 0, a3 = 0;
#pragma unroll
    for (int t = 0; t < 8; ++t) {
        const int k = t * 256 + lane * 4;
        float4 xv = *(const float4*)(xr + k);
        float4 w0 = *(const float4*)(Wg + (size_t)k * NG);
        float4 w1 = *(const float4*)(Wg + (size_t)k * NG + 4);
        float4 w2 = *(const float4*)(Wg + (size_t)k * NG + 8);
        float4 w3 = *(const float4*)(Wg + (size_t)k * NG + 12);
        a0 = fmaf(xv.x, w0.x, a0); a0 = fmaf(xv.y, w1.x, a0);
        a0 = fmaf(xv.z, w2.x, a0); a0 = fmaf(xv.w, w3.x, a0);
        a1 = fmaf(xv.x, w0.y, a1); a1 = fmaf(xv.y, w1.y, a1);
        a1 = fmaf(xv.z, w2.y, a1); a1 = fmaf(xv.w, w3.y, a1);
        a2 = fmaf(xv.x, w0.z, a2); a2 = fmaf(xv.y, w1.z, a2);
        a2 = fmaf(xv.z, w2.z, a2); a2 = fmaf(xv.w, w3.z, a2);
        a3 = fmaf(xv.x, w0.w, a3); a3 = fmaf(xv.y, w1.w, a3);
        a3 = fmaf(xv.z, w2.w, a3); a3 = fmaf(xv.w, w3.w, a3);
    }
#pragma unroll
    for (int m = 32; m; m >>= 1) {
        a0 += __shfl_xor(a0, m, 64);
        a1 += __shfl_xor(a1, m, 64);
        a2 += __shfl_xor(a2, m, 64);
        a3 += __shfl_xor(a3, m, 64);
    }
    if (lane == 0) {
        float4 r; r.x = a0; r.y = a1; r.z = a2; r.w = a3;
        *(float4*)(Gl + (size_t)n * NG) = r;
    }
}

// ---------------------------------------------------------------------------
// Kernel 5: per-token gating finalize. One thread per token. All arrays
// statically indexed (unrolled) -> registers, no scratch.
// jax.lax.top_k tie-break = lowest index: strict-'>' scans from index 0.
// ---------------------------------------------------------------------------
__global__ __launch_bounds__(256) void finalize_kernel(
    const float* __restrict__ El, const float* __restrict__ Gl,
    const float* __restrict__ conf, const float* __restrict__ bgp,
    const float* __restrict__ bep, const float* __restrict__ prp,
    float* __restrict__ out)
{
    const int n = blockIdx.x * 256 + threadIdx.x;

    // ---- group softmax + top2 groups ----
    float gl0 = Gl[(size_t)n * NG + 0] + bgp[0];
    float gl1 = Gl[(size_t)n * NG + 1] + bgp[1];
    float gl2 = Gl[(size_t)n * NG + 2] + bgp[2];
    float gl3 = Gl[(size_t)n * NG + 3] + bgp[3];
    float gm = fmaxf(fmaxf(gl0, gl1), fmaxf(gl2, gl3));
    float e0 = expf(gl0 - gm), e1 = expf(gl1 - gm);
    float e2 = expf(gl2 - gm), e3 = expf(gl3 - gm);
    float gs = e0 + e1 + e2 + e3;
    float gp0 = e0 / gs, gp1 = e1 / gs, gp2 = e2 / gs, gp3 = e3 / gs;

    int g0 = 0; float t0 = gp0;
    if (gp1 > t0) { t0 = gp1; g0 = 1; }
    if (gp2 > t0) { t0 = gp2; g0 = 2; }
    if (gp3 > t0) { t0 = gp3; g0 = 3; }
    int g1 = -1; float t1 = -1.0f;
    if (g0 != 0)              { t1 = gp0; g1 = 0; }
    if (g0 != 1 && gp1 > t1)  { t1 = gp1; g1 = 1; }
    if (g0 != 2 && gp2 > t1)  { t1 = gp2; g1 = 2; }
    if (g0 != 3 && gp3 > t1)  { t1 = gp3; g1 = 3; }

    const float c = conf[n];
    const float uni = (1.0f - c) * (1.0f / 16.0f);

    int ci0, ci1, ci2, ci3;
    float cv0, cv1, cv2, cv3;

    auto proc = [&](int gid, float tp, int& ia, float& va, int& ib, float& vb) {
        const float* base = El + (size_t)n * NE + gid * EPG;
        const float* beb = bep + gid * EPG;
        const float* prb = prp + gid * EPG;
        float lv[16];
#pragma unroll
        for (int e = 0; e < 16; ++e) lv[e] = (base[e] + beb[e]) * prb[e];
        float m = lv[0];
#pragma unroll
        for (int e = 1; e < 16; ++e) m = fmaxf(m, lv[e]);
        float pe[16]; float s = 0.0f;
#pragma unroll
        for (int e = 0; e < 16; ++e) { pe[e] = expf(lv[e] - m); s += pe[e]; }
        const float cs = c / s;
        float bl[16];
#pragma unroll
        for (int e = 0; e < 16; ++e) bl[e] = fmaf(pe[e], cs, uni);
        int i0 = 0; float v0 = bl[0];
#pragma unroll
        for (int e = 1; e < 16; ++e) { if (bl[e] > v0) { v0 = bl[e]; i0 = e; } }
        int i1 = -1; float v1 = -1e30f;
#pragma unroll
        for (int e = 0; e < 16; ++e) {
            if (e != i0 && bl[e] > v1) { v1 = bl[e]; i1 = e; }
        }
        ia = gid * EPG + i0; va = v0 * tp;
        ib = gid * EPG + i1; vb = v1 * tp;
    };
    proc(g0, t0, ci0, cv0, ci1, cv1);
    proc(g1, t1, ci2, cv2, ci3, cv3);

    // ---- normalize + final top2 of the 4 candidates ----
    const float wsum = cv0 + cv1 + cv2 + cv3;
    const float winv = 1.0f / (wsum + 1e-9f);
    const float s0 = cv0 * winv, s1 = cv1 * winv;
    const float s2 = cv2 * winv, s3 = cv3 * winv;

    float bv = s0; int bi = ci0; int bslot = 0;
    if (s1 > bv || (s1 == bv && ci1 < bi)) { bv = s1; bi = ci1; bslot = 1; }
    if (s2 > bv || (s2 == bv && ci2 < bi)) { bv = s2; bi = ci2; bslot = 2; }
    if (s3 > bv || (s3 == bv && ci3 < bi)) { bv = s3; bi = ci3; bslot = 3; }
    float sv = -1.0f; int si = 1 << 30;
    if (bslot != 0 && (s0 > sv || (s0 == sv && ci0 < si))) { sv = s0; si = ci0; }
    if (bslot != 1 && (s1 > sv || (s1 == sv && ci1 < si))) { sv = s1; si = ci1; }
    if (bslot != 2 && (s2 > sv || (s2 == sv && ci2 < si))) { sv = s2; si = ci2; }
    if (bslot != 3 && (s3 > sv || (s3 == sv && ci3 < si))) { sv = s3; si = ci3; }

    // ---- write dispatch row + identical combine row ----
    float* d0 = out + (size_t)n * NE;
    float* d1 = out + (size_t)NTOK * NE + (size_t)n * NE;
#pragma unroll
    for (int q = 0; q < 16; ++q) {
        const int j = q * 4;
        float4 v;
        v.x = (j + 0 == bi) ? bv : ((j + 0 == si) ? sv : 0.0f);
        v.y = (j + 1 == bi) ? bv : ((j + 1 == si) ? sv : 0.0f);
        v.z = (j + 2 == bi) ? bv : ((j + 2 == si) ? sv : 0.0f);
        v.w = (j + 3 == bi) ? bv : ((j + 3 == si) ? sv : 0.0f);
        *(float4*)(d0 + j) = v;
        *(float4*)(d1 + j) = v;
    }
    if (n == 0) out[(size_t)2 * NTOK * NE] = 0.0f;   // aux_loss
}

// ---------------------------------------------------------------------------
extern "C" void kernel_launch(void* const* d_in, const int* in_sizes, int n_in,
                              void* d_out, int out_size, void* d_ws, size_t ws_size,
                              hipStream_t stream)
{
    const float* x    = (const float*)d_in[0];
    const float* Wg   = (const float*)d_in[1];
    const float* bg   = (const float*)d_in[2];
    const float* We   = (const float*)d_in[3];
    const float* be   = (const float*)d_in[4];
    const float* Wc1  = (const float*)d_in[5];
    const float* bc1  = (const float*)d_in[6];
    const float* Wc2  = (const float*)d_in[7];
    const float* bc2  = (const float*)d_in[8];
    const float* prio = (const float*)d_in[9];
    float* out = (float*)d_out;

    // workspace layout (floats): h[16384*512] | conf[16384] | El[16384*64] | Gl[16384*4]
    float* h    = (float*)d_ws;
    float* conf = h + (size_t)NTOK * HD4;
    float* El   = conf + NTOK;
    float* Gl   = El + (size_t)NTOK * NE;

    gemm_conf_kernel<<<dim3(NTOK / 128, HD4 / 128), 256, 0, stream>>>(x, Wc1, bc1, h);
    conf_reduce_kernel<<<NTOK / 4, 256, 0, stream>>>(h, Wc2, bc2, conf);
    gemm_experts_kernel<<<NTOK / 64, 256, 0, stream>>>(x, We, El);
    gemv_gates_kernel<<<NTOK / 4, 256, 0, stream>>>(x, Wg, Gl);
    finalize_kernel<<<NTOK / 256, 256, 0, stream>>>(El, Gl, conf, bg, be, prio, out);
}